// Round 6
// baseline (702.805 us; speedup 1.0000x reference)
//
#include <hip/hip_runtime.h>
#include <hip/hip_bf16.h>

#define NTOK 4096   // B*N
#define NN   512

typedef __attribute__((ext_vector_type(8))) short bf16x8;
typedef __attribute__((ext_vector_type(4))) short bf16x4;
typedef __attribute__((ext_vector_type(4))) float f32x4;

__device__ __forceinline__ float bf16_to_f(unsigned short u) {
    unsigned int x = ((unsigned int)u) << 16;
    return __builtin_bit_cast(float, x);
}
__device__ __forceinline__ unsigned short f_to_bf16(float f) {
    unsigned int b = __builtin_bit_cast(unsigned int, f);
    return (unsigned short)((b + 0x7fff + ((b >> 16) & 1)) >> 16);
}
__device__ __forceinline__ bf16x8 pack8(float4 a, float4 b) {
    bf16x8 v;
    v[0]=(short)f_to_bf16(a.x); v[1]=(short)f_to_bf16(a.y);
    v[2]=(short)f_to_bf16(a.z); v[3]=(short)f_to_bf16(a.w);
    v[4]=(short)f_to_bf16(b.x); v[5]=(short)f_to_bf16(b.y);
    v[6]=(short)f_to_bf16(b.z); v[7]=(short)f_to_bf16(b.w);
    return v;
}

// ---------------------------------------------------------------------------
// K0: detect whether relations_mask is 1-byte bool or 4-byte int.
__global__ void detect_mask_kernel(const unsigned char* __restrict__ m, int* __restrict__ flag) {
    __shared__ int f;
    if (threadIdx.x == 0) f = 0;
    __syncthreads();
    int any = 0;
    for (int i = threadIdx.x; i < 4096; i += 256) {
        if ((i & 3) != 0 && m[i] != 0) any = 1;
    }
    if (any) atomicOr(&f, 1);
    __syncthreads();
    if (threadIdx.x == 0) *flag = f;   // 1 => byte mask, 0 => int32 mask
}

// ---------------------------------------------------------------------------
// K0b: rel16[i] = mask[i] ? relations[i] : -1   (int16). 2 elems/thread.
__global__ __launch_bounds__(256) void prep_rel16(
    const int* __restrict__ rel, const void* __restrict__ mask,
    const int* __restrict__ flag, short* __restrict__ rel16)
{
    const bool mbyte = (*flag != 0);
    const unsigned char* m8 = (const unsigned char*)mask;
    const int* m32 = (const int*)mask;
    const int i = (blockIdx.x * 256 + threadIdx.x) * 2;
    int2 rv = *(const int2*)(rel + i);
    int ok0, ok1;
    if (mbyte) { ok0 = m8[i]; ok1 = m8[i + 1]; }
    else       { ok0 = (m32[i] != 0); ok1 = (m32[i + 1] != 0); }
    short2 o;
    o.x = ok0 ? (short)rv.x : (short)-1;
    o.y = ok1 ? (short)rv.y : (short)-1;
    *(short2*)(rel16 + i) = o;
}

// ---------------------------------------------------------------------------
// K1: x[row,d] = relu(sum_e embed[tok[row]][e] * W_in[e][d] + b_in[d])
__global__ __launch_bounds__(256) void embed_proj_kernel(
    const int* __restrict__ tok, const float* __restrict__ embed,
    const float* __restrict__ W_in, const float* __restrict__ b_in,
    float* __restrict__ x)
{
    __shared__ float emb[8][304];
    __shared__ int tloc[8];
    const int t = threadIdx.x;
    const int r0 = blockIdx.x * 8;
    if (t < 8) tloc[t] = tok[r0 + t];
    __syncthreads();
    for (int i = t; i < 8 * 300; i += 256) {
        int r = i / 300, e = i - r * 300;
        emb[r][e] = embed[(size_t)tloc[r] * 300 + e];
    }
    __syncthreads();
    float acc[8] = {0.f,0.f,0.f,0.f,0.f,0.f,0.f,0.f};
    const int d = t;
    for (int e = 0; e < 300; ++e) {
        float w = W_in[e * 256 + d];
#pragma unroll
        for (int r = 0; r < 8; ++r) acc[r] += emb[r][e] * w;
    }
    const float bb = b_in[d];
#pragma unroll
    for (int r = 0; r < 8; ++r) {
        float o = acc[r] + bb;
        o = o > 0.f ? o : 0.f;
        x[(size_t)(r0 + r) * 256 + d] = o;
    }
}

// ---------------------------------------------------------------------------
// K2: MFMA bf16 GEMM, double-buffered LDS + register prefetch.
__global__ __launch_bounds__(256) void gemm_mfma(
    const float* __restrict__ A,
    const float* __restrict__ W0, const float* __restrict__ W1p, const float* __restrict__ W2p,
    int ncPerW, const float* __restrict__ bias,
    float* __restrict__ C, int M, int K, int Nc, int relu)
{
    __shared__ unsigned short As[2][64][40];
    __shared__ unsigned short Bs[2][64][40];

    const int t = threadIdx.x;
    const int lane = t & 63, w = t >> 6;
    const int g = lane >> 4, li = lane & 15;
    const int r0 = blockIdx.y * 64, c0 = blockIdx.x * 64;

    const float* Wp = W0; int cW = c0;
    if (c0 >= 2 * ncPerW)      { Wp = W2p; cW = c0 - 2 * ncPerW; }
    else if (c0 >= ncPerW)     { Wp = W1p; cW = c0 - ncPerW; }

    f32x4 acc[4];
#pragma unroll
    for (int i = 0; i < 4; ++i) acc[i] = (f32x4){0.f, 0.f, 0.f, 0.f};

    const int arow = t >> 2, ad8 = (t & 3) * 8;
    const int bnn = t & 63, bk8 = (t >> 6) * 8;

    const float* ap0 = A + (size_t)(r0 + arow) * K + ad8;
    float4 a0 = *(const float4*)ap0;
    float4 a1 = *(const float4*)(ap0 + 4);
    float wv[8];
#pragma unroll
    for (int j = 0; j < 8; ++j)
        wv[j] = Wp[(size_t)(bk8 + j) * ncPerW + cW + bnn];

    const int nk = K >> 5;
    for (int ki = 0; ki < nk; ++ki) {
        const int cur = ki & 1;
        *(bf16x8*)&As[cur][arow][ad8] = pack8(a0, a1);
        {
            bf16x8 v;
#pragma unroll
            for (int j = 0; j < 8; ++j) v[j] = (short)f_to_bf16(wv[j]);
            *(bf16x8*)&Bs[cur][bnn][bk8] = v;
        }
        if (ki + 1 < nk) {
            const int k0 = (ki + 1) * 32;
            const float* ap = A + (size_t)(r0 + arow) * K + k0 + ad8;
            a0 = *(const float4*)ap;
            a1 = *(const float4*)(ap + 4);
#pragma unroll
            for (int j = 0; j < 8; ++j)
                wv[j] = Wp[(size_t)(k0 + bk8 + j) * ncPerW + cW + bnn];
        }
        __syncthreads();
        bf16x8 af = *(const bf16x8*)&As[cur][16 * w + li][g * 8];
#pragma unroll
        for (int sub = 0; sub < 4; ++sub) {
            bf16x8 bfr = *(const bf16x8*)&Bs[cur][16 * sub + li][g * 8];
            acc[sub] = __builtin_amdgcn_mfma_f32_16x16x32_bf16(af, bfr, acc[sub], 0, 0, 0);
        }
    }
#pragma unroll
    for (int sub = 0; sub < 4; ++sub) {
        int col = c0 + sub * 16 + li;
        float bv = bias ? bias[col] : 0.f;
#pragma unroll
        for (int r = 0; r < 4; ++r) {
            int row = r0 + 16 * w + g * 4 + r;
            float o = acc[sub][r] + bv;
            if (relu) o = fmaxf(o, 0.f);
            C[(size_t)row * Nc + col] = o;
        }
    }
}

// ---------------------------------------------------------------------------
// K3: relation-aware attention, m-split 4-way. Block = (b,chunk,ms,h), 2048
// blocks, 4 waves. K-fragments load global->reg directly (no LDS); V via LDS
// transpose; loads for tile t+1 issue right AFTER the barrier (T14). Partial
// z/sm written unnormalized to zpart/smpart; combine kernel normalizes.
__global__ __launch_bounds__(256, 3) void attn_mfma(
    const float* __restrict__ qkv,       // [BN, 768] (q|k|v)
    const short* __restrict__ rel16,     // [B,N,N] mask-folded relations
    const float* __restrict__ relk_g,    // [100,32]
    const float* __restrict__ relv_g,
    float* __restrict__ zpart,           // [4][4096][256]
    float* __restrict__ smpart)          // [4][4096][8]
{
    const int p = blockIdx.x;            // 0..2047
    const int cx = p & 7, kk = p >> 3;   // kk 0..255
    const int sg = cx * 32 + (kk >> 3);  // quarter-slice id 0..255 (XCD-grouped)
    const int h  = kk & 7;
    const int b = sg >> 5, chunk = (sg >> 2) & 7, ms = sg & 3;
    const int n0 = chunk * 64, mbase = ms * 128;

    const int t = threadIdx.x;
    const int lane = t & 63, w = t >> 6;
    const int g = lane >> 4, li = lane & 15;
    const int qrow = 16 * w + g * 4;     // +r

    __shared__ float wrel[64][100];            // 25600 B (partial, this m-slice)
    __shared__ unsigned short qrk[64][100];    // 12800 B
    __shared__ union {
        unsigned short relk_s[100][40];        // 8000 B
        unsigned short relvT[32][136];         // 8704 B
        struct {
            unsigned short v_t[2][32][40];     // 5120 B [buf][d][m]
            unsigned short p_s[4][16][40];     // 5120 B per-wave P
        } mn;                                  // 10240 B
    } u;                                       // total 48640 B -> 3 blocks/CU

    // ---- Phase A: zero wrel, stage relk, load Q frag
    for (int i = t; i < 6400; i += 256) ((float*)wrel)[i] = 0.f;
    for (int i = t; i < 400; i += 256) {
        int rr = i >> 2, d8 = (i & 3) * 8;
        const float* sp = relk_g + rr * 32 + d8;
        *(bf16x8*)&u.relk_s[rr][d8] = pack8(*(const float4*)sp, *(const float4*)(sp + 4));
    }
    const float scale = 0.17677669529663687f;
    bf16x8 qf;
    {
        const float* qp = qkv + (size_t)(b * NN + n0 + 16 * w + li) * 768 + h * 32 + g * 8;
        float4 q0 = *(const float4*)qp, q1 = *(const float4*)(qp + 4);
        q0.x *= scale; q0.y *= scale; q0.z *= scale; q0.w *= scale;
        q1.x *= scale; q1.y *= scale; q1.z *= scale; q1.w *= scale;
        qf = pack8(q0, q1);
    }

    // per-lane rel rows and staging maps
    const short* relrow[4];
#pragma unroll
    for (int r = 0; r < 4; ++r)
        relrow[r] = rel16 + ((size_t)b * NN + n0 + qrow + r) * NN;
    const int vm = t & 31, vdg = t >> 5;
    const size_t kRB = (size_t)(b * NN) * 768 + 256 + h * 32 + g * 8;   // + m*768
    const size_t vRB = (size_t)(b * NN) * 768 + 512 + h * 32 + vdg * 4; // + m*768

    // tile-0 loads issued before first barrier
    float4 kld[4][4]; float4 vld[4]; short rld[4][8];
    {
        const int m0 = mbase;
        kld[0][0] = *(const float4*)(qkv + kRB + (size_t)(m0 + li) * 768);
        kld[0][1] = *(const float4*)(qkv + kRB + (size_t)(m0 + li) * 768 + 4);
        kld[0][2] = *(const float4*)(qkv + kRB + (size_t)(m0 + 16 + li) * 768);
        kld[0][3] = *(const float4*)(qkv + kRB + (size_t)(m0 + 16 + li) * 768 + 4);
        vld[0]    = *(const float4*)(qkv + vRB + (size_t)(m0 + vm) * 768);
#pragma unroll
        for (int idx = 0; idx < 8; ++idx)
            rld[0][idx] = relrow[idx & 3][m0 + (idx >> 2) * 16 + li];
    }
    __syncthreads();

    // ---- Phase B: qrk = Q @ relk^T
#pragma unroll
    for (int rc = 0; rc < 7; ++rc) {
        bf16x8 bb = *(const bf16x8*)&u.relk_s[rc * 16 + li][g * 8];
        f32x4 s = __builtin_amdgcn_mfma_f32_16x16x32_bf16(qf, bb, (f32x4){0.f,0.f,0.f,0.f}, 0, 0, 0);
        int col = rc * 16 + li;
        if (col < 100) {
#pragma unroll
            for (int r = 0; r < 4; ++r)
                qrk[qrow + r][col] = f_to_bf16(s[r]);
        }
    }
    __syncthreads();   // relk reads done; union free for v_t/p_s

    float smacc[4] = {0.f, 0.f, 0.f, 0.f};
    f32x4 zf[2];
    zf[0] = (f32x4){0.f,0.f,0.f,0.f};
    zf[1] = (f32x4){0.f,0.f,0.f,0.f};

    // ---- Main loop: 4 m-tiles of 32, fully unrolled
#pragma unroll
    for (int tt = 0; tt < 4; ++tt) {
        const int cur = tt & 1;
        {   // write V tile transposed [32 d][32 m] (waits only on vld[tt])
            float4 vv = vld[tt];
            u.mn.v_t[cur][vdg * 4 + 0][vm] = f_to_bf16(vv.x);
            u.mn.v_t[cur][vdg * 4 + 1][vm] = f_to_bf16(vv.y);
            u.mn.v_t[cur][vdg * 4 + 2][vm] = f_to_bf16(vv.z);
            u.mn.v_t[cur][vdg * 4 + 3][vm] = f_to_bf16(vv.w);
        }
        __syncthreads();
        // pack this tile's K frags from regs (no LDS for K)
        bf16x8 kf0 = pack8(kld[tt][0], kld[tt][1]);
        bf16x8 kf1 = pack8(kld[tt][2], kld[tt][3]);
        short rcur[8];
#pragma unroll
        for (int idx = 0; idx < 8; ++idx) rcur[idx] = rld[tt][idx];
        // T14: issue next tile's loads EARLY (hide under compute below)
        if (tt + 1 < 4) {
            const int m0n = mbase + (tt + 1) * 32;
            kld[tt+1][0] = *(const float4*)(qkv + kRB + (size_t)(m0n + li) * 768);
            kld[tt+1][1] = *(const float4*)(qkv + kRB + (size_t)(m0n + li) * 768 + 4);
            kld[tt+1][2] = *(const float4*)(qkv + kRB + (size_t)(m0n + 16 + li) * 768);
            kld[tt+1][3] = *(const float4*)(qkv + kRB + (size_t)(m0n + 16 + li) * 768 + 4);
            vld[tt+1]    = *(const float4*)(qkv + vRB + (size_t)(m0n + vm) * 768);
#pragma unroll
            for (int idx = 0; idx < 8; ++idx)
                rld[tt+1][idx] = relrow[idx & 3][m0n + (idx >> 2) * 16 + li];
        }
        // QK^T
        f32x4 s0 = __builtin_amdgcn_mfma_f32_16x16x32_bf16(qf, kf0, (f32x4){0.f,0.f,0.f,0.f}, 0, 0, 0);
        f32x4 s1 = __builtin_amdgcn_mfma_f32_16x16x32_bf16(qf, kf1, (f32x4){0.f,0.f,0.f,0.f}, 0, 0, 0);
        // scores -> p (exp, no max-sub: scores O(1)), wrel scatter, p_s store
        float pr[8];
#pragma unroll
        for (int idx = 0; idx < 8; ++idx) {
            const int r = idx & 3;
            const int rl = rcur[idx];
            const int rla = rl < 0 ? 0 : rl;
            const float qadd = bf16_to_f(qrk[qrow + r][rla]);
            const float sv = ((idx >> 2) ? s1[r] : s0[r]) + qadd;
            float pv = 0.f;
            if (rl >= 0) {
                pv = __expf(fminf(sv, 50.f));
                atomicAdd(&wrel[qrow + r][rl], pv);
            }
            smacc[r] += pv;
            pr[idx] = pv;
        }
#pragma unroll
        for (int idx = 0; idx < 8; ++idx)
            u.mn.p_s[w][g * 4 + (idx & 3)][(idx >> 2) * 16 + li] = f_to_bf16(pr[idx]);

        asm volatile("s_waitcnt lgkmcnt(0)" ::: "memory");
        __builtin_amdgcn_sched_barrier(0);
        // PV: z += P @ V
        bf16x8 pa = *(const bf16x8*)&u.mn.p_s[w][li][g * 8];
#pragma unroll
        for (int dc = 0; dc < 2; ++dc) {
            bf16x8 vb = *(const bf16x8*)&u.mn.v_t[cur][dc * 16 + li][g * 8];
            zf[dc] = __builtin_amdgcn_mfma_f32_16x16x32_bf16(pa, vb, zf[dc], 0, 0, 0);
        }
    }
    __syncthreads();   // wrel atomics complete; main-loop LDS free

    // ---- stage relv TRANSPOSED: relvT[d][rel]; zero rel 100..135
    for (int i = t; i < 32 * 36; i += 256) {
        int d = i / 36, c = 100 + (i - (i / 36) * 36);
        u.relvT[d][c] = 0;
    }
    for (int i = t; i < 400; i += 256) {
        int rr2 = i >> 2, d8 = (i & 3) * 8;
        const float* sp = relv_g + rr2 * 32 + d8;
        float4 s0 = *(const float4*)sp, s1 = *(const float4*)(sp + 4);
        u.relvT[d8 + 0][rr2] = f_to_bf16(s0.x);
        u.relvT[d8 + 1][rr2] = f_to_bf16(s0.y);
        u.relvT[d8 + 2][rr2] = f_to_bf16(s0.z);
        u.relvT[d8 + 3][rr2] = f_to_bf16(s0.w);
        u.relvT[d8 + 4][rr2] = f_to_bf16(s1.x);
        u.relvT[d8 + 5][rr2] = f_to_bf16(s1.y);
        u.relvT[d8 + 6][rr2] = f_to_bf16(s1.z);
        u.relvT[d8 + 7][rr2] = f_to_bf16(s1.w);
    }
    __syncthreads();

    // ---- z += Wpartial @ relv
#pragma unroll
    for (int kc = 0; kc < 4; ++kc) {
        const int kbase = kc * 32 + g * 8;
        const float* wp = &wrel[16 * w + li][0];
        bf16x8 af;
#pragma unroll
        for (int j = 0; j < 8; ++j) {
            int idx = kbase + j;
            float val = (idx < 100) ? wp[idx] : 0.f;
            af[j] = (short)f_to_bf16(val);
        }
#pragma unroll
        for (int dc = 0; dc < 2; ++dc) {
            bf16x8 vb = *(const bf16x8*)&u.relvT[dc * 16 + li][kbase];
            zf[dc] = __builtin_amdgcn_mfma_f32_16x16x32_bf16(af, vb, zf[dc], 0, 0, 0);
        }
    }

    // ---- reduce sm over the 16 m-lanes; write unnormalized partials
#pragma unroll
    for (int r = 0; r < 4; ++r) {
        smacc[r] += __shfl_xor(smacc[r], 1, 64);
        smacc[r] += __shfl_xor(smacc[r], 2, 64);
        smacc[r] += __shfl_xor(smacc[r], 4, 64);
        smacc[r] += __shfl_xor(smacc[r], 8, 64);
    }
#pragma unroll
    for (int r = 0; r < 4; ++r) {
        const int row = b * NN + n0 + qrow + r;
        size_t ob = (size_t)ms * 1048576 + (size_t)row * 256 + h * 32;
#pragma unroll
        for (int dc = 0; dc < 2; ++dc)
            zpart[ob + dc * 16 + li] = zf[dc][r];
        if (li == 0)
            smpart[(size_t)ms * 32768 + (size_t)row * 8 + h] = smacc[r];
    }
}

// ---------------------------------------------------------------------------
// K3b: z[row][c] = (sum_s zpart[s][row][c]) / (sum_s smpart[s][row][c/32])
__global__ __launch_bounds__(256) void combine_kernel(
    const float* __restrict__ zpart, const float* __restrict__ smpart,
    float* __restrict__ z)
{
    const int t = threadIdx.x;
    const int wi = t >> 6, lane = t & 63;
    const int row = blockIdx.x * 4 + wi;
    const int h = lane >> 3;
    float den = 0.f;
    float4 acc = make_float4(0.f, 0.f, 0.f, 0.f);
#pragma unroll
    for (int s = 0; s < 4; ++s) {
        den += smpart[(size_t)s * 32768 + (size_t)row * 8 + h];
        float4 v = *(const float4*)(zpart + (size_t)s * 1048576 + (size_t)row * 256 + lane * 4);
        acc.x += v.x; acc.y += v.y; acc.z += v.z; acc.w += v.w;
    }
    const float inv = 1.f / den;
    acc.x *= inv; acc.y *= inv; acc.z *= inv; acc.w *= inv;
    *(float4*)(z + (size_t)row * 256 + lane * 4) = acc;
}

// ---------------------------------------------------------------------------
// K4: x = LayerNorm(xin + y) * g + b
__global__ __launch_bounds__(256) void ln_kernel(
    const float* __restrict__ xin, const float* __restrict__ y,
    const float* __restrict__ g, const float* __restrict__ bsh,
    float* __restrict__ xout)
{
    const int t = threadIdx.x;
    const int w = t >> 6, lane = t & 63;
    const size_t row = (size_t)blockIdx.x * 4 + w;
    const float4 xv = *(const float4*)(xin + row * 256 + lane * 4);
    const float4 yv = *(const float4*)(y + row * 256 + lane * 4);
    float4 sv;
    sv.x = xv.x + yv.x; sv.y = xv.y + yv.y; sv.z = xv.z + yv.z; sv.w = xv.w + yv.w;
    float sum = sv.x + sv.y + sv.z + sv.w;
    float sq  = sv.x * sv.x + sv.y * sv.y + sv.z * sv.z + sv.w * sv.w;
#pragma unroll
    for (int off = 1; off < 64; off <<= 1) {
        sum += __shfl_xor(sum, off, 64);
        sq  += __shfl_xor(sq, off, 64);
    }
    const float mu = sum * (1.f / 256.f);
    const float var = sq * (1.f / 256.f) - mu * mu;
    const float rs = rsqrtf(var + 1e-5f);
    const float4 gv = *(const float4*)(g + lane * 4);
    const float4 bv = *(const float4*)(bsh + lane * 4);
    float4 o;
    o.x = (sv.x - mu) * rs * gv.x + bv.x;
    o.y = (sv.y - mu) * rs * gv.y + bv.y;
    o.z = (sv.z - mu) * rs * gv.z + bv.z;
    o.w = (sv.w - mu) * rs * gv.w + bv.w;
    *(float4*)(xout + row * 256 + lane * 4) = o;
}

// ---------------------------------------------------------------------------
extern "C" void kernel_launch(void* const* d_in, const int* in_sizes, int n_in,
                              void* d_out, int out_size, void* d_ws, size_t ws_size,
                              hipStream_t stream)
{
    (void)in_sizes; (void)n_in; (void)out_size;
    const int*   tok   = (const int*)d_in[0];
    const int*   rel   = (const int*)d_in[1];
    const void*  mask  = d_in[2];
    const float* embed = (const float*)d_in[3];
    const float* W_in  = (const float*)d_in[4];
    const float* b_in  = (const float*)d_in[5];
    const float* Wq    = (const float*)d_in[6];
    const float* Wk    = (const float*)d_in[7];
    const float* Wv    = (const float*)d_in[8];
    const float* Wo    = (const float*)d_in[9];
    const float* ln1g  = (const float*)d_in[10];
    const float* ln1b  = (const float*)d_in[11];
    const float* ln2g  = (const float*)d_in[12];
    const float* ln2b  = (const float*)d_in[13];
    const float* W1    = (const float*)d_in[14];
    const float* b1    = (const float*)d_in[15];
    const float* W2    = (const float*)d_in[16];
    const float* b2    = (const float*)d_in[17];
    const float* relk  = (const float*)d_in[18];
    const float* relv  = (const float*)d_in[19];
    const float* Wout  = (const float*)d_in[20];
    const float* bout  = (const float*)d_in[21];
    float* out = (float*)d_out;

    float* ws  = (float*)d_ws;
    float* x   = ws;                       // 1M floats
    float* z   = ws + (1u << 20);          // 1M (combine output; also rel16 home if tight)
    float* zo  = ws + 2u * (1u << 20);     // 1M (also smpart during attn)
    float* qkv = ws + 3u * (1u << 20);     // 3M
    float* hb  = ws + 6u * (1u << 20);     // 4M (FFN hidden; also zpart during attn)

    // rel16 is 4MB (1M floats). Dedicated slot if ws allows, else alias z
    // (attn reads rel16 before combine overwrites z; re-prep each layer).
    const bool roomy = ws_size >= ((size_t)45 << 20);
    short* rel16 = roomy ? (short*)(ws + 10u * (1u << 20)) : (short*)z;
    int*   flag  = (int*)(ws + (roomy ? 11u : 10u) * (1u << 20));
    float* zpart = hb;      // 4M floats = [4][4096][256]
    float* smpart = zo;     // 128K floats = [4][4096][8]

    detect_mask_kernel<<<1, 256, 0, stream>>>((const unsigned char*)mask, flag);
    if (roomy)
        prep_rel16<<<4096, 256, 0, stream>>>(rel, mask, flag, rel16);
    embed_proj_kernel<<<512, 256, 0, stream>>>(tok, embed, W_in, b_in, x);

    for (int l = 0; l < 4; ++l) {
        const float* wq = Wq + (size_t)l * 65536;
        const float* wk = Wk + (size_t)l * 65536;
        const float* wv = Wv + (size_t)l * 65536;
        const float* wo = Wo + (size_t)l * 65536;
        const float* w1 = W1 + (size_t)l * 262144;
        const float* w2 = W2 + (size_t)l * 262144;

        if (!roomy)
            prep_rel16<<<4096, 256, 0, stream>>>(rel, mask, flag, rel16);

        gemm_mfma<<<dim3(12, 64), 256, 0, stream>>>(x, wq, wk, wv, 256, nullptr,
                                                    qkv, NTOK, 256, 768, 0);
        attn_mfma<<<2048, 256, 0, stream>>>(qkv, rel16, relk, relv, zpart, smpart);
        combine_kernel<<<1024, 256, 0, stream>>>(zpart, smpart, z);
        gemm_mfma<<<dim3(4, 64), 256, 0, stream>>>(z, wo, wo, wo, 256, nullptr,
                                                   zo, NTOK, 256, 256, 0);
        ln_kernel<<<1024, 256, 0, stream>>>(x, zo, ln1g + l * 256, ln1b + l * 256, x);
        gemm_mfma<<<dim3(16, 64), 256, 0, stream>>>(x, w1, w1, w1, 1024, b1 + l * 1024,
                                                    hb, NTOK, 256, 1024, 1);
        gemm_mfma<<<dim3(4, 64), 256, 0, stream>>>(hb, w2, w2, w2, 256, b2 + l * 256,
                                                   zo, NTOK, 1024, 256, 0);
        ln_kernel<<<1024, 256, 0, stream>>>(x, zo, ln2g + l * 256, ln2b + l * 256, x);
    }
    gemm_mfma<<<dim3(4, 64), 256, 0, stream>>>(x, Wout, Wout, Wout, 256, bout,
                                               out, NTOK, 256, 256, 0);
}